// Round 9
// baseline (1185.008 us; speedup 1.0000x reference)
//
#include <hip/hip_runtime.h>

// ---------------------------------------------------------------------------
// Self-attention forward via fp16 split-MFMA (round 13).
//   R12 (reg ping-pong + sched_barrier pins) REGRESSED qk8 91->97 us: pinning
//   fought the compiler's already-good intra-wave interleave. R13 reverts
//   qk8 to the R11-proven body (91 us) and adds ONE safe change: wave-group
//   phase stagger. Waves 0-3 process B-quarters in order 0,1,2,3; waves 4-7
//   in order 2,3,0,1 (group key w&4 => each SIMD hosts one wave of each
//   group under either wave->SIMD mapping). With __syncthreads releasing all
//   waves in phase, both waves/SIMD otherwise burst-read then burst-MFMA
//   together; staggering makes one wave MFMA while the other reads,
//   overlapping the LDS pipe (2304 cyc/chunk) under the MFMA pipe (3098).
//   Pure work permutation inside the valid buffer: no new sync, no pins,
//   static acc indices in both branches, identical barrier structure.
// ---------------------------------------------------------------------------

typedef _Float16 half8 __attribute__((ext_vector_type(8)));
typedef _Float16 half4v __attribute__((ext_vector_type(4)));
typedef float floatx4 __attribute__((ext_vector_type(4)));

__device__ __forceinline__ void glds16(const _Float16* g, _Float16* l) {
    __builtin_amdgcn_global_load_lds(
        (const __attribute__((address_space(1))) void*)g,
        (__attribute__((address_space(3))) void*)l, 16, 0, 0);
}

// ---------------------------------------------------------------------------
// qk8 v6: Sc = (QK^T)*scale + per-row/block partial max. M=N=4096, K=1024.
//   256x256 tile, 8 waves (4M x 2N), grid 16x16 = 1 block/CU.
//   32 chunks of K=32; chunk c in buf c&1; panels QH|QL|KH|KL at half-offsets
//   0|8192|16384|24576 within a buf, buf stride 32768 (128 KB total).
//   Loop body (proven R11 skeleton):
//     __syncthreads();                   // buf c&1 valid; other buf reusable
//     if (c<31) stageAll((c+1)&1, ..);   // 8 DMAs, land by next barrier
//     read A (8 ds_read); per q (stagger-ordered): B frags (4 ds_read)
//     + 24 MFMA (3 split terms x 4mi x 2nj)
//   LDS layout: per panel [128 LDS rows][64 halves]; LDS row j holds source
//   rows {2j,2j+1} x k32; slot s of row r holds source slot s^(r&7)
//   (source slot = (R&1)*4+quad) — conflict-free (measured 0 in R7/R11);
//   DMA source column pre-swizzled with the same involution.
// ---------------------------------------------------------------------------

#define QQUAD(Q)                                                               \
    do {                                                                       \
        half8 bh[2], bl[2];                                                    \
        _Pragma("unroll") for (int nj = 0; nj < 2; ++nj) {                     \
            bh[nj] = *(const half8*)&sP[cb + 16384 + (brow2 + (Q)*16 + nj*8)*64 + s0h]; \
            bl[nj] = *(const half8*)&sP[cb + 24576 + (brow2 + (Q)*16 + nj*8)*64 + s0h]; \
        }                                                                      \
        __builtin_amdgcn_s_setprio(1);                                         \
        _Pragma("unroll") for (int mi = 0; mi < 4; ++mi)                       \
            _Pragma("unroll") for (int nj = 0; nj < 2; ++nj) {                 \
                acc[mi][(Q)*2+nj] = __builtin_amdgcn_mfma_f32_16x16x32_f16(    \
                    aH[mi], bh[nj], acc[mi][(Q)*2+nj], 0, 0, 0);               \
                acc[mi][(Q)*2+nj] = __builtin_amdgcn_mfma_f32_16x16x32_f16(    \
                    aH[mi], bl[nj], acc[mi][(Q)*2+nj], 0, 0, 0);               \
                acc[mi][(Q)*2+nj] = __builtin_amdgcn_mfma_f32_16x16x32_f16(    \
                    aL[mi], bh[nj], acc[mi][(Q)*2+nj], 0, 0, 0);               \
            }                                                                  \
        __builtin_amdgcn_s_setprio(0);                                         \
    } while (0)

__global__ __launch_bounds__(512, 2) void qk8(
    const _Float16* __restrict__ QH, const _Float16* __restrict__ QL,
    const _Float16* __restrict__ KH, const _Float16* __restrict__ KL,
    float* __restrict__ Sc, float* __restrict__ pmax, float scale)
{
    __shared__ _Float16 sP[2 * 32768];   // 2 bufs x 4 panels x [128][64]

    const int tid = threadIdx.x;
    const int bm = blockIdx.y, bn = blockIdx.x;
    const int lane = tid & 63, w = tid >> 6;
    const int quad = lane >> 4, lrow = lane & 15;
    const int wm = w >> 1, wn = w & 1;          // 4M x 2N wave grid

    // read addressing: slot = ((lrow&1)*4+quad) ^ ((lrow>>1)&7); row pairs
    const int s0h = ((((lrow & 1) << 2) + quad) ^ ((lrow >> 1) & 7)) * 8;
    const int arow2 = wm * 32 + (lrow >> 1);    // A LDS-row base (+ mi*8)
    const int brow2 = wn * 64 + (lrow >> 1);    // B LDS-row base (+ q*16+nj*8)

    // staging: thread tid fills LDS halves tid*8 per sweep; inverse swizzle
    const int sp = (tid & 7) ^ ((tid >> 3) & 7);
    const int gR = 2 * (tid >> 3) + (sp >> 2);  // source row 0..127 (sweep 1)
    const int gk = (sp & 3) * 8;                // source k-halves 0..24
    const size_t ga = (size_t)(bm * 256 + gR) * 1024 + gk;
    const size_t gb = (size_t)(bn * 256 + gR) * 1024 + gk;

    floatx4 acc[4][8] = {};

    auto stageAll = [&](int b, int ko) {        // 8 glds: 4 panels x 2 sweeps
        _Float16* l = sP + b * 32768 + tid * 8;
        glds16(QH + ga + ko, l);
        glds16(QH + ga + ko + 131072, l + 4096);   // +128 source rows
        glds16(QL + ga + ko, l + 8192);
        glds16(QL + ga + ko + 131072, l + 12288);
        glds16(KH + gb + ko, l + 16384);
        glds16(KH + gb + ko + 131072, l + 20480);
        glds16(KL + gb + ko, l + 24576);
        glds16(KL + gb + ko + 131072, l + 28672);
    };

    // Prologue: stage chunk 0 into buf 0.
    stageAll(0, 0);

    #pragma unroll 1
    for (int c = 0; c < 32; ++c) {
        __syncthreads();   // drains vmcnt+lgkmcnt: buf c&1 valid, other free

        if (c < 31) stageAll((c + 1) & 1, (c + 1) * 32);

        const int cb = (c & 1) * 32768;
        half8 aH[4], aL[4];
        #pragma unroll
        for (int mi = 0; mi < 4; ++mi) {
            aH[mi] = *(const half8*)&sP[cb + (arow2 + mi * 8) * 64 + s0h];
            aL[mi] = *(const half8*)&sP[cb + 8192 + (arow2 + mi * 8) * 64 + s0h];
        }
        // Wave-group phase stagger: each SIMD hosts one wave of each group,
        // so one wave's MFMA overlaps the other's B-quarter ds_reads.
        if ((w & 4) == 0) {
            QQUAD(0); QQUAD(1); QQUAD(2); QQUAD(3);
        } else {
            QQUAD(2); QQUAD(3); QQUAD(0); QQUAD(1);
        }
    }

    // Defensive drain: no DMAs should be outstanding (c=31 stages nothing),
    // but a wave must never reach s_endpgm with LDS-DMAs in flight.
    asm volatile("s_waitcnt vmcnt(0) lgkmcnt(0)" ::: "memory");

    // Epilogue: C/D layout row = quad*4+reg, col = lane&15 (m89-verified).
    #pragma unroll
    for (int mi = 0; mi < 4; ++mi) {
        #pragma unroll
        for (int r = 0; r < 4; ++r) {
            const int grow = bm * 256 + wm * 64 + mi * 16 + quad * 4 + r;
            float v[8];
            #pragma unroll
            for (int nc = 0; nc < 8; ++nc) v[nc] = acc[mi][nc][r] * scale;
            float mx = fmaxf(fmaxf(fmaxf(v[0], v[1]), fmaxf(v[2], v[3])),
                             fmaxf(fmaxf(v[4], v[5]), fmaxf(v[6], v[7])));
            #pragma unroll
            for (int off = 1; off < 16; off <<= 1)
                mx = fmaxf(mx, __shfl_xor(mx, off));
            if (lrow == 0) pmax[(size_t)grow * 32 + bn * 2 + wn] = mx;
            float* so = Sc + (size_t)grow * 4096 + bn * 256 + wn * 128;
            #pragma unroll
            for (int nc = 0; nc < 8; ++nc) so[nc * 16 + lrow] = v[nc];
        }
    }
}

// ---------------------------------------------------------------------------
// R4 gemm_nt kernel, unchanged: used for projections (split), V^T and PV.
// ---------------------------------------------------------------------------

// OMODE: 0 = f32 out (acc*scale), 1 = f32 out (acc*scale/rdiv[row]),
//        2 = half out (acc*scale), 3 = split half out (hi,lo of acc*scale)
template <bool SPLITIN, int OMODE, bool PMAX>
__global__ __launch_bounds__(256, 2) void gemm_nt(
    const _Float16* __restrict__ AH, const _Float16* __restrict__ AL,
    const _Float16* BH, const _Float16* BL,
    void* out0, void* out1,
    const float* __restrict__ rdiv, float* __restrict__ pmax,
    float scale, int M, int N, int K,
    const _Float16* BH2, const _Float16* BL2, void* o0b, void* o1b)
{
    if (blockIdx.z == 1) { BH = BH2; BL = BL2; out0 = o0b; out1 = o1b; }

    __shared__ _Float16 sAH[2 * 128 * 32];
    __shared__ _Float16 sBH[2 * 128 * 32];
    __shared__ _Float16 sAL[SPLITIN ? 2 * 128 * 32 : 8];
    __shared__ _Float16 sBL[SPLITIN ? 2 * 128 * 32 : 8];

    const int tid = threadIdx.x;
    const int bm = blockIdx.y, bn = blockIdx.x;
    const int lane = tid & 63, quad = lane >> 4, lrow = lane & 15;
    const int wave = tid >> 6, wm = wave >> 1, wn = wave & 1;

    const int wb = (tid & 192) * 8;
    const size_t g0 = (size_t)(tid >> 2) * K + (tid & 3) * 8;
    const size_t g1 = (size_t)((256 + tid) >> 2) * K + (tid & 3) * 8;
    const _Float16* pA0 = AH + (size_t)bm * 128 * K + g0;
    const _Float16* pA1 = AH + (size_t)bm * 128 * K + g1;
    const _Float16* pB0 = BH + (size_t)bn * 128 * K + g0;
    const _Float16* pB1 = BH + (size_t)bn * 128 * K + g1;
    const _Float16* pA0L = SPLITIN ? (AL + (size_t)bm * 128 * K + g0) : nullptr;
    const _Float16* pA1L = SPLITIN ? (AL + (size_t)bm * 128 * K + g1) : nullptr;
    const _Float16* pB0L = SPLITIN ? (BL + (size_t)bn * 128 * K + g0) : nullptr;
    const _Float16* pB1L = SPLITIN ? (BL + (size_t)bn * 128 * K + g1) : nullptr;

    floatx4 acc[4][4] = {};

    const int aoff = (wm * 64 + lrow) * 32 + quad * 8;
    const int boff = (wn * 64 + lrow) * 32 + quad * 8;

    glds16(pA0, sAH + wb);        glds16(pA1, sAH + 2048 + wb);
    glds16(pB0, sBH + wb);        glds16(pB1, sBH + 2048 + wb);
    if (SPLITIN) {
        glds16(pA0L, sAL + wb);   glds16(pA1L, sAL + 2048 + wb);
        glds16(pB0L, sBL + wb);   glds16(pB1L, sBL + 2048 + wb);
    }
    pA0 += 32; pA1 += 32; pB0 += 32; pB1 += 32;
    if (SPLITIN) { pA0L += 32; pA1L += 32; pB0L += 32; pB1L += 32; }

    int cur = 0;
    for (int k0 = 0; k0 < K; k0 += 32) {
        __syncthreads();

        if (k0 + 32 < K) {
            const int nb = (cur ^ 1) * 4096;
            glds16(pA0, sAH + nb + wb);        glds16(pA1, sAH + nb + 2048 + wb);
            glds16(pB0, sBH + nb + wb);        glds16(pB1, sBH + nb + 2048 + wb);
            if (SPLITIN) {
                glds16(pA0L, sAL + nb + wb);   glds16(pA1L, sAL + nb + 2048 + wb);
                glds16(pB0L, sBL + nb + wb);   glds16(pB1L, sBL + nb + 2048 + wb);
            }
            pA0 += 32; pA1 += 32; pB0 += 32; pB1 += 32;
            if (SPLITIN) { pA0L += 32; pA1L += 32; pB0L += 32; pB1L += 32; }
        }

        const int cb = cur * 4096;
        half8 aH[4], bH[4], aL[4], bL[4];
        #pragma unroll
        for (int i = 0; i < 4; ++i) {
            aH[i] = *(const half8*)&sAH[cb + aoff + i * 16 * 32];
            bH[i] = *(const half8*)&sBH[cb + boff + i * 16 * 32];
            if (SPLITIN) {
                aL[i] = *(const half8*)&sAL[cb + aoff + i * 16 * 32];
                bL[i] = *(const half8*)&sBL[cb + boff + i * 16 * 32];
            }
        }
        #pragma unroll
        for (int mi = 0; mi < 4; ++mi)
            #pragma unroll
            for (int nj = 0; nj < 4; ++nj) {
                acc[mi][nj] = __builtin_amdgcn_mfma_f32_16x16x32_f16(
                    aH[mi], bH[nj], acc[mi][nj], 0, 0, 0);
                if (SPLITIN) {
                    acc[mi][nj] = __builtin_amdgcn_mfma_f32_16x16x32_f16(
                        aH[mi], bL[nj], acc[mi][nj], 0, 0, 0);
                    acc[mi][nj] = __builtin_amdgcn_mfma_f32_16x16x32_f16(
                        aL[mi], bH[nj], acc[mi][nj], 0, 0, 0);
                }
            }
        cur ^= 1;
    }

    #pragma unroll
    for (int mi = 0; mi < 4; ++mi) {
        #pragma unroll
        for (int r = 0; r < 4; ++r) {
            const int grow = bm * 128 + wm * 64 + mi * 16 + quad * 4 + r;
            float s = scale;
            if (OMODE == 1) s = scale / rdiv[grow];
            float v[4];
            #pragma unroll
            for (int nj = 0; nj < 4; ++nj) v[nj] = acc[mi][nj][r] * s;
            if (PMAX) {
                float mx = fmaxf(fmaxf(v[0], v[1]), fmaxf(v[2], v[3]));
                #pragma unroll
                for (int off = 1; off < 16; off <<= 1)
                    mx = fmaxf(mx, __shfl_xor(mx, off));
                if (lrow == 0) pmax[(size_t)grow * 64 + bn * 2 + wn] = mx;
            }
            #pragma unroll
            for (int nj = 0; nj < 4; ++nj) {
                const int gcol = bn * 128 + wn * 64 + nj * 16 + lrow;
                const size_t idx = (size_t)grow * N + gcol;
                if (OMODE <= 1) {
                    ((float*)out0)[idx] = v[nj];
                } else if (OMODE == 2) {
                    ((_Float16*)out0)[idx] = (_Float16)v[nj];
                } else {
                    const _Float16 h = (_Float16)v[nj];
                    ((_Float16*)out0)[idx] = h;
                    ((_Float16*)out1)[idx] = (_Float16)(v[nj] - (float)h);
                }
            }
        }
    }
}

// x -> 256x split into fp16 hi/lo.
__global__ __launch_bounds__(256) void split_scale(
    const float* __restrict__ x, _Float16* __restrict__ hi,
    _Float16* __restrict__ lo, int n)
{
    int i = (blockIdx.x * 256 + threadIdx.x) * 4;
    const int stride = gridDim.x * 256 * 4;
    for (; i < n; i += stride) {
        float4 v = *(const float4*)(x + i);
        float a[4] = {v.x * 256.f, v.y * 256.f, v.z * 256.f, v.w * 256.f};
        half4v h, l;
        #pragma unroll
        for (int j = 0; j < 4; ++j) {
            h[j] = (_Float16)a[j];
            l[j] = (_Float16)(a[j] - (float)h[j]);
        }
        *(half4v*)(hi + i) = h;
        *(half4v*)(lo + i) = l;
    }
}

// W [dim][dim] fp32 -> 256*W^T split fp16 hi/lo; z picks {WQ, WK, WV}.
__global__ __launch_bounds__(256) void wprep3(
    const float* __restrict__ W0, const float* __restrict__ W1,
    const float* __restrict__ W2,
    _Float16* __restrict__ h0, _Float16* __restrict__ l0,
    _Float16* __restrict__ h1, _Float16* __restrict__ l1,
    _Float16* __restrict__ h2, int dim)
{
    const int z = blockIdx.z;
    const float* W = (z == 0) ? W0 : (z == 1) ? W1 : W2;
    _Float16* hiT = (z == 0) ? h0 : (z == 1) ? h1 : h2;
    _Float16* loT = (z == 0) ? l0 : (z == 1) ? l1 : nullptr;

    __shared__ float t[32][33];
    const int n0 = blockIdx.x * 32, k0 = blockIdx.y * 32;
    const int tx = threadIdx.x, ty = threadIdx.y;  // block (32,8)
    #pragma unroll
    for (int i = 0; i < 4; ++i)
        t[ty + 8 * i][tx] = 256.f * W[(size_t)(k0 + ty + 8 * i) * dim + n0 + tx];
    __syncthreads();
    #pragma unroll
    for (int i = 0; i < 4; ++i) {
        const int nn = ty + 8 * i;
        const float v = t[tx][nn];  // 256*W[k0+tx][n0+nn]
        const _Float16 h = (_Float16)v;
        const size_t o = (size_t)(n0 + nn) * dim + k0 + tx;
        hiT[o] = h;
        if (loT) loT[o] = (_Float16)(v - (float)h);
    }
}

// One block per row: single pass. rowmax from pmax partials (32/row from qk8);
// P = exp(s - rowmax) fp16 (unnormalized), rowsum fp32.
__global__ __launch_bounds__(256) void softmax_p(
    const float* __restrict__ Sc, const float* __restrict__ pmax,
    _Float16* __restrict__ P, float* __restrict__ rowsum)
{
    __shared__ float red[8];
    const int tid = threadIdx.x;
    const int row = blockIdx.x;
    const float* srow = Sc + (size_t)row * 4096;
    _Float16* prow = P + (size_t)row * 4096;

    if (tid < 32) {
        float m = pmax[(size_t)row * 32 + tid];
        #pragma unroll
        for (int off = 16; off; off >>= 1) m = fmaxf(m, __shfl_xor(m, off));
        if (tid == 0) red[0] = m;
    }
    __syncthreads();
    const float rmax = red[0];

    float s = 0.f;
    for (int c = tid * 4; c < 4096; c += 1024) {
        float4 v = *(const float4*)(srow + c);
        float p0 = __expf(v.x - rmax), p1 = __expf(v.y - rmax);
        float p2 = __expf(v.z - rmax), p3 = __expf(v.w - rmax);
        s += p0 + p1 + p2 + p3;
        half4v h = {(_Float16)p0, (_Float16)p1, (_Float16)p2, (_Float16)p3};
        *(half4v*)(prow + c) = h;
    }
    #pragma unroll
    for (int off = 32; off; off >>= 1) s += __shfl_xor(s, off, 64);
    if ((tid & 63) == 0) red[4 + (tid >> 6)] = s;
    __syncthreads();
    if (tid == 0) rowsum[row] = red[4] + red[5] + red[6] + red[7];
}

extern "C" void kernel_launch(void* const* d_in, const int* in_sizes, int n_in,
                              void* d_out, int out_size, void* d_ws, size_t ws_size,
                              hipStream_t stream) {
    const int Bb = 4, S = 4096, D = 1024;
    const size_t SD = (size_t)S * D;      // 4.19M
    const size_t SS = (size_t)S * S;      // 16.8M

    const float* x  = (const float*)d_in[0];
    const float* WQ = (const float*)d_in[1];
    const float* WK = (const float*)d_in[2];
    const float* WV = (const float*)d_in[3];
    float* out = (float*)d_out;

    // Workspace layout (~168 MB; ws_size in [209.7, 218) MB per R0 probe).
    char* w = (char*)d_ws;
    _Float16* WQhT = (_Float16*)w;  w += (size_t)D * D * 2;
    _Float16* WQlT = (_Float16*)w;  w += (size_t)D * D * 2;
    _Float16* WKhT = (_Float16*)w;  w += (size_t)D * D * 2;
    _Float16* WKlT = (_Float16*)w;  w += (size_t)D * D * 2;
    _Float16* WvhT = (_Float16*)w;  w += (size_t)D * D * 2;
    _Float16* xhi  = (_Float16*)w;  w += SD * 2;
    _Float16* xlo  = (_Float16*)w;  w += SD * 2;
    _Float16* Qhi  = (_Float16*)w;  w += SD * 2;
    _Float16* Qlo  = (_Float16*)w;  w += SD * 2;
    _Float16* Khi  = (_Float16*)w;  w += SD * 2;
    _Float16* Klo  = (_Float16*)w;  w += SD * 2;
    _Float16* VT   = (_Float16*)w;  w += SD * 2;
    float*    rowsum = (float*)w;   w += (size_t)S * 4;
    float*    pmax = (float*)w;     w += (size_t)S * 64 * 4;
    float*    Sc   = (float*)w;     w += SS * 4;
    _Float16* P    = (_Float16*)w;  w += SS * 2;

    const float kInv256 = 0.00390625f;           // 2^-8
    const float kScScale = 4.76837158203125e-7f; // 2^-21 = 1/(65536*32)

    dim3 blk(256);

    // Weight prep: 256*W^T split fp16 (Wv: hi only), one z=3 launch.
    wprep3<<<dim3(32, 32, 3), dim3(32, 8), 0, stream>>>(
        WQ, WK, WV, WQhT, WQlT, WKhT, WKlT, WvhT, D);

    for (int b = 0; b < Bb; ++b) {
        const float* xb = x + (size_t)b * SD;
        float* outb = out + (size_t)b * SD;

        split_scale<<<dim3(4096), blk, 0, stream>>>(xb, xhi, xlo, (int)SD);

        // Q and K projections (z-fused): [4096x1024] = split(x') @ split(W'^T)
        gemm_nt<true, 3, false><<<dim3(D / 128, S / 128, 2), blk, 0, stream>>>(
            xhi, xlo, WQhT, WQlT, Qhi, Qlo, nullptr, nullptr, kInv256, S, D, D,
            WKhT, WKlT, Khi, Klo);

        // VT'' = 256*V^T: [1024x4096] = WvhT' @ xhi'^T
        gemm_nt<false, 2, false><<<dim3(S / 128, D / 128, 1), blk, 0, stream>>>(
            WvhT, nullptr, xhi, nullptr, VT, nullptr, nullptr, nullptr, kInv256,
            D, S, D, nullptr, nullptr, nullptr, nullptr);

        // Sc = QK^T/32 fp32 + partial rowmax: [4096x4096], 256^2 dedup chunks.
        qk8<<<dim3(S / 256, S / 256), dim3(512), 0, stream>>>(
            Qhi, Qlo, Khi, Klo, Sc, pmax, kScScale);

        softmax_p<<<dim3(S), blk, 0, stream>>>(Sc, pmax, P, rowsum);

        // Z = (P @ V) / rowsum: [4096x1024], acc = 256*PV -> *2^-8/rowsum
        gemm_nt<false, 1, false><<<dim3(D / 128, S / 128, 1), blk, 0, stream>>>(
            P, nullptr, VT, nullptr, outb, nullptr, rowsum, nullptr, kInv256,
            S, D, S, nullptr, nullptr, nullptr, nullptr);
    }
}

// Round 10
// 1073.970 us; speedup vs baseline: 1.1034x; 1.1034x over previous
//
#include <hip/hip_runtime.h>

// ---------------------------------------------------------------------------
// Self-attention forward via fp16 split-MFMA (round 14).
//   qk8 plateaued at ~91 us across 3 schedule variants (R12 pin regressed,
//   R13 stagger neutral) => revert qk8 to the measured-best R11 body and
//   pivot to the non-qk8 ~800 us. Structural defect found: the PV gemm runs
//   256 blocks = 1 block/CU (4 waves/CU) with K=4096 = 128 serial chunks —
//   every per-chunk __syncthreads DMA-drain is exposed (no co-resident block
//   to cover it). R14: PV split-K2 via blockIdx.z (z picks K-half; new Kst
//   stride param vs K loop bound; z-branch offsets A/B by koff) => 512
//   blocks = 2 blocks/CU, 64 chunks/block; f32 partials + pv_fin combine
//   out = (p0+p1)*2^-8/rowsum. gemm_nt body untouched (addressing only).
// ---------------------------------------------------------------------------

typedef _Float16 half8 __attribute__((ext_vector_type(8)));
typedef _Float16 half4v __attribute__((ext_vector_type(4)));
typedef float floatx4 __attribute__((ext_vector_type(4)));

__device__ __forceinline__ void glds16(const _Float16* g, _Float16* l) {
    __builtin_amdgcn_global_load_lds(
        (const __attribute__((address_space(1))) void*)g,
        (__attribute__((address_space(3))) void*)l, 16, 0, 0);
}

// ---------------------------------------------------------------------------
// qk8 (R11 body, measured 91.2 us): Sc = (QK^T)*scale + partial rowmax.
//   256x256 tile, 8 waves (4M x 2N), grid 16x16 = 1 block/CU.
//   32 chunks of K=32; chunk c in buf c&1; panels QH|QL|KH|KL at half-offsets
//   0|8192|16384|24576, buf stride 32768 (128 KB). Dedup: all four panels in
//   LDS once per chunk, 3 MFMA terms per fragment-set.
// ---------------------------------------------------------------------------

__global__ __launch_bounds__(512, 2) void qk8(
    const _Float16* __restrict__ QH, const _Float16* __restrict__ QL,
    const _Float16* __restrict__ KH, const _Float16* __restrict__ KL,
    float* __restrict__ Sc, float* __restrict__ pmax, float scale)
{
    __shared__ _Float16 sP[2 * 32768];   // 2 bufs x 4 panels x [128][64]

    const int tid = threadIdx.x;
    const int bm = blockIdx.y, bn = blockIdx.x;
    const int lane = tid & 63, w = tid >> 6;
    const int quad = lane >> 4, lrow = lane & 15;
    const int wm = w >> 1, wn = w & 1;          // 4M x 2N wave grid

    // read addressing: slot = ((lrow&1)*4+quad) ^ ((lrow>>1)&7); row pairs
    const int s0h = ((((lrow & 1) << 2) + quad) ^ ((lrow >> 1) & 7)) * 8;
    const int arow2 = wm * 32 + (lrow >> 1);    // A LDS-row base (+ mi*8)
    const int brow2 = wn * 64 + (lrow >> 1);    // B LDS-row base (+ q*16+nj*8)

    // staging: thread tid fills LDS halves tid*8 per sweep; inverse swizzle
    const int sp = (tid & 7) ^ ((tid >> 3) & 7);
    const int gR = 2 * (tid >> 3) + (sp >> 2);  // source row 0..127 (sweep 1)
    const int gk = (sp & 3) * 8;                // source k-halves 0..24
    const size_t ga = (size_t)(bm * 256 + gR) * 1024 + gk;
    const size_t gb = (size_t)(bn * 256 + gR) * 1024 + gk;

    floatx4 acc[4][8] = {};

    auto stageAll = [&](int b, int ko) {        // 8 glds: 4 panels x 2 sweeps
        _Float16* l = sP + b * 32768 + tid * 8;
        glds16(QH + ga + ko, l);
        glds16(QH + ga + ko + 131072, l + 4096);   // +128 source rows
        glds16(QL + ga + ko, l + 8192);
        glds16(QL + ga + ko + 131072, l + 12288);
        glds16(KH + gb + ko, l + 16384);
        glds16(KH + gb + ko + 131072, l + 20480);
        glds16(KL + gb + ko, l + 24576);
        glds16(KL + gb + ko + 131072, l + 28672);
    };

    // Prologue: stage chunk 0 into buf 0.
    stageAll(0, 0);

    #pragma unroll 1
    for (int c = 0; c < 32; ++c) {
        __syncthreads();   // drains vmcnt+lgkmcnt: buf c&1 valid, other free

        if (c < 31) stageAll((c + 1) & 1, (c + 1) * 32);

        const int cb = (c & 1) * 32768;
        half8 aH[4], aL[4];
        #pragma unroll
        for (int mi = 0; mi < 4; ++mi) {
            aH[mi] = *(const half8*)&sP[cb + (arow2 + mi * 8) * 64 + s0h];
            aL[mi] = *(const half8*)&sP[cb + 8192 + (arow2 + mi * 8) * 64 + s0h];
        }
        #pragma unroll
        for (int q = 0; q < 4; ++q) {
            half8 bh[2], bl[2];
            #pragma unroll
            for (int nj = 0; nj < 2; ++nj) {
                bh[nj] = *(const half8*)&sP[cb + 16384 + (brow2 + q * 16 + nj * 8) * 64 + s0h];
                bl[nj] = *(const half8*)&sP[cb + 24576 + (brow2 + q * 16 + nj * 8) * 64 + s0h];
            }
            __builtin_amdgcn_s_setprio(1);
            #pragma unroll
            for (int mi = 0; mi < 4; ++mi)
                #pragma unroll
                for (int nj = 0; nj < 2; ++nj) {
                    acc[mi][q * 2 + nj] = __builtin_amdgcn_mfma_f32_16x16x32_f16(
                        aH[mi], bh[nj], acc[mi][q * 2 + nj], 0, 0, 0);
                    acc[mi][q * 2 + nj] = __builtin_amdgcn_mfma_f32_16x16x32_f16(
                        aH[mi], bl[nj], acc[mi][q * 2 + nj], 0, 0, 0);
                    acc[mi][q * 2 + nj] = __builtin_amdgcn_mfma_f32_16x16x32_f16(
                        aL[mi], bh[nj], acc[mi][q * 2 + nj], 0, 0, 0);
                }
            __builtin_amdgcn_s_setprio(0);
        }
    }

    // Defensive drain: a wave must never reach s_endpgm with LDS-DMAs in
    // flight (LDS dealloc while DMA pending => fault/corruption).
    asm volatile("s_waitcnt vmcnt(0) lgkmcnt(0)" ::: "memory");

    // Epilogue: C/D layout row = quad*4+reg, col = lane&15 (m89-verified).
    #pragma unroll
    for (int mi = 0; mi < 4; ++mi) {
        #pragma unroll
        for (int r = 0; r < 4; ++r) {
            const int grow = bm * 256 + wm * 64 + mi * 16 + quad * 4 + r;
            float v[8];
            #pragma unroll
            for (int nc = 0; nc < 8; ++nc) v[nc] = acc[mi][nc][r] * scale;
            float mx = fmaxf(fmaxf(fmaxf(v[0], v[1]), fmaxf(v[2], v[3])),
                             fmaxf(fmaxf(v[4], v[5]), fmaxf(v[6], v[7])));
            #pragma unroll
            for (int off = 1; off < 16; off <<= 1)
                mx = fmaxf(mx, __shfl_xor(mx, off));
            if (lrow == 0) pmax[(size_t)grow * 32 + bn * 2 + wn] = mx;
            float* so = Sc + (size_t)grow * 4096 + bn * 256 + wn * 128;
            #pragma unroll
            for (int nc = 0; nc < 8; ++nc) so[nc * 16 + lrow] = v[nc];
        }
    }
}

// ---------------------------------------------------------------------------
// gemm_nt: R4 body + (Kst, koff) addressing params for split-K.
//   K = loop bound; Kst = row stride of A/B; z==1 branch adds koff to A and
//   switches B/out (proj fuse passes koff=0 => byte-identical behavior).
// OMODE: 0 = f32 out (acc*scale), 1 = f32 out (acc*scale/rdiv[row]),
//        2 = half out (acc*scale), 3 = split half out (hi,lo of acc*scale)
// ---------------------------------------------------------------------------
template <bool SPLITIN, int OMODE, bool PMAX>
__global__ __launch_bounds__(256, 2) void gemm_nt(
    const _Float16* AH, const _Float16* AL,
    const _Float16* BH, const _Float16* BL,
    void* out0, void* out1,
    const float* __restrict__ rdiv, float* __restrict__ pmax,
    float scale, int M, int N, int K, int Kst, int koff,
    const _Float16* BH2, const _Float16* BL2, void* o0b, void* o1b)
{
    if (blockIdx.z == 1) {
        BH = BH2; BL = BL2; out0 = o0b; out1 = o1b;
        AH += koff;
        if (SPLITIN) AL += koff;
    }

    __shared__ _Float16 sAH[2 * 128 * 32];
    __shared__ _Float16 sBH[2 * 128 * 32];
    __shared__ _Float16 sAL[SPLITIN ? 2 * 128 * 32 : 8];
    __shared__ _Float16 sBL[SPLITIN ? 2 * 128 * 32 : 8];

    const int tid = threadIdx.x;
    const int bm = blockIdx.y, bn = blockIdx.x;
    const int lane = tid & 63, quad = lane >> 4, lrow = lane & 15;
    const int wave = tid >> 6, wm = wave >> 1, wn = wave & 1;

    const int wb = (tid & 192) * 8;
    const size_t g0 = (size_t)(tid >> 2) * Kst + (tid & 3) * 8;
    const size_t g1 = (size_t)((256 + tid) >> 2) * Kst + (tid & 3) * 8;
    const _Float16* pA0 = AH + (size_t)bm * 128 * Kst + g0;
    const _Float16* pA1 = AH + (size_t)bm * 128 * Kst + g1;
    const _Float16* pB0 = BH + (size_t)bn * 128 * Kst + g0;
    const _Float16* pB1 = BH + (size_t)bn * 128 * Kst + g1;
    const _Float16* pA0L = SPLITIN ? (AL + (size_t)bm * 128 * Kst + g0) : nullptr;
    const _Float16* pA1L = SPLITIN ? (AL + (size_t)bm * 128 * Kst + g1) : nullptr;
    const _Float16* pB0L = SPLITIN ? (BL + (size_t)bn * 128 * Kst + g0) : nullptr;
    const _Float16* pB1L = SPLITIN ? (BL + (size_t)bn * 128 * Kst + g1) : nullptr;

    floatx4 acc[4][4] = {};

    const int aoff = (wm * 64 + lrow) * 32 + quad * 8;
    const int boff = (wn * 64 + lrow) * 32 + quad * 8;

    glds16(pA0, sAH + wb);        glds16(pA1, sAH + 2048 + wb);
    glds16(pB0, sBH + wb);        glds16(pB1, sBH + 2048 + wb);
    if (SPLITIN) {
        glds16(pA0L, sAL + wb);   glds16(pA1L, sAL + 2048 + wb);
        glds16(pB0L, sBL + wb);   glds16(pB1L, sBL + 2048 + wb);
    }
    pA0 += 32; pA1 += 32; pB0 += 32; pB1 += 32;
    if (SPLITIN) { pA0L += 32; pA1L += 32; pB0L += 32; pB1L += 32; }

    int cur = 0;
    for (int k0 = 0; k0 < K; k0 += 32) {
        __syncthreads();

        if (k0 + 32 < K) {
            const int nb = (cur ^ 1) * 4096;
            glds16(pA0, sAH + nb + wb);        glds16(pA1, sAH + nb + 2048 + wb);
            glds16(pB0, sBH + nb + wb);        glds16(pB1, sBH + nb + 2048 + wb);
            if (SPLITIN) {
                glds16(pA0L, sAL + nb + wb);   glds16(pA1L, sAL + nb + 2048 + wb);
                glds16(pB0L, sBL + nb + wb);   glds16(pB1L, sBL + nb + 2048 + wb);
            }
            pA0 += 32; pA1 += 32; pB0 += 32; pB1 += 32;
            if (SPLITIN) { pA0L += 32; pA1L += 32; pB0L += 32; pB1L += 32; }
        }

        const int cb = cur * 4096;
        half8 aH[4], bH[4], aL[4], bL[4];
        #pragma unroll
        for (int i = 0; i < 4; ++i) {
            aH[i] = *(const half8*)&sAH[cb + aoff + i * 16 * 32];
            bH[i] = *(const half8*)&sBH[cb + boff + i * 16 * 32];
            if (SPLITIN) {
                aL[i] = *(const half8*)&sAL[cb + aoff + i * 16 * 32];
                bL[i] = *(const half8*)&sBL[cb + boff + i * 16 * 32];
            }
        }
        #pragma unroll
        for (int mi = 0; mi < 4; ++mi)
            #pragma unroll
            for (int nj = 0; nj < 4; ++nj) {
                acc[mi][nj] = __builtin_amdgcn_mfma_f32_16x16x32_f16(
                    aH[mi], bH[nj], acc[mi][nj], 0, 0, 0);
                if (SPLITIN) {
                    acc[mi][nj] = __builtin_amdgcn_mfma_f32_16x16x32_f16(
                        aH[mi], bL[nj], acc[mi][nj], 0, 0, 0);
                    acc[mi][nj] = __builtin_amdgcn_mfma_f32_16x16x32_f16(
                        aL[mi], bH[nj], acc[mi][nj], 0, 0, 0);
                }
            }
        cur ^= 1;
    }

    #pragma unroll
    for (int mi = 0; mi < 4; ++mi) {
        #pragma unroll
        for (int r = 0; r < 4; ++r) {
            const int grow = bm * 128 + wm * 64 + mi * 16 + quad * 4 + r;
            float s = scale;
            if (OMODE == 1) s = scale / rdiv[grow];
            float v[4];
            #pragma unroll
            for (int nj = 0; nj < 4; ++nj) v[nj] = acc[mi][nj][r] * s;
            if (PMAX) {
                float mx = fmaxf(fmaxf(v[0], v[1]), fmaxf(v[2], v[3]));
                #pragma unroll
                for (int off = 1; off < 16; off <<= 1)
                    mx = fmaxf(mx, __shfl_xor(mx, off));
                if (lrow == 0) pmax[(size_t)grow * 64 + bn * 2 + wn] = mx;
            }
            #pragma unroll
            for (int nj = 0; nj < 4; ++nj) {
                const int gcol = bn * 128 + wn * 64 + nj * 16 + lrow;
                const size_t idx = (size_t)grow * N + gcol;
                if (OMODE <= 1) {
                    ((float*)out0)[idx] = v[nj];
                } else if (OMODE == 2) {
                    ((_Float16*)out0)[idx] = (_Float16)v[nj];
                } else {
                    const _Float16 h = (_Float16)v[nj];
                    ((_Float16*)out0)[idx] = h;
                    ((_Float16*)out1)[idx] = (_Float16)(v[nj] - (float)h);
                }
            }
        }
    }
}

// PV split-K combine: out[s,d] = (p0+p1)[s,d] * scale / rowsum[s].
__global__ __launch_bounds__(256) void pv_fin(
    const float* __restrict__ p, const float* __restrict__ rowsum,
    float* __restrict__ out, float scale, int n)
{
    int i = (blockIdx.x * 256 + threadIdx.x) * 4;
    const int stride = gridDim.x * 256 * 4;
    for (; i < n; i += stride) {
        float4 a = *(const float4*)(p + i);
        float4 b = *(const float4*)(p + i + n);
        const float r = scale / rowsum[i >> 10];   // N=1024, f4 never crosses rows
        float4 o;
        o.x = (a.x + b.x) * r; o.y = (a.y + b.y) * r;
        o.z = (a.z + b.z) * r; o.w = (a.w + b.w) * r;
        *(float4*)(out + i) = o;
    }
}

// x -> 256x split into fp16 hi/lo.
__global__ __launch_bounds__(256) void split_scale(
    const float* __restrict__ x, _Float16* __restrict__ hi,
    _Float16* __restrict__ lo, int n)
{
    int i = (blockIdx.x * 256 + threadIdx.x) * 4;
    const int stride = gridDim.x * 256 * 4;
    for (; i < n; i += stride) {
        float4 v = *(const float4*)(x + i);
        float a[4] = {v.x * 256.f, v.y * 256.f, v.z * 256.f, v.w * 256.f};
        half4v h, l;
        #pragma unroll
        for (int j = 0; j < 4; ++j) {
            h[j] = (_Float16)a[j];
            l[j] = (_Float16)(a[j] - (float)h[j]);
        }
        *(half4v*)(hi + i) = h;
        *(half4v*)(lo + i) = l;
    }
}

// W [dim][dim] fp32 -> 256*W^T split fp16 hi/lo; z picks {WQ, WK, WV}.
__global__ __launch_bounds__(256) void wprep3(
    const float* __restrict__ W0, const float* __restrict__ W1,
    const float* __restrict__ W2,
    _Float16* __restrict__ h0, _Float16* __restrict__ l0,
    _Float16* __restrict__ h1, _Float16* __restrict__ l1,
    _Float16* __restrict__ h2, int dim)
{
    const int z = blockIdx.z;
    const float* W = (z == 0) ? W0 : (z == 1) ? W1 : W2;
    _Float16* hiT = (z == 0) ? h0 : (z == 1) ? h1 : h2;
    _Float16* loT = (z == 0) ? l0 : (z == 1) ? l1 : nullptr;

    __shared__ float t[32][33];
    const int n0 = blockIdx.x * 32, k0 = blockIdx.y * 32;
    const int tx = threadIdx.x, ty = threadIdx.y;  // block (32,8)
    #pragma unroll
    for (int i = 0; i < 4; ++i)
        t[ty + 8 * i][tx] = 256.f * W[(size_t)(k0 + ty + 8 * i) * dim + n0 + tx];
    __syncthreads();
    #pragma unroll
    for (int i = 0; i < 4; ++i) {
        const int nn = ty + 8 * i;
        const float v = t[tx][nn];  // 256*W[k0+tx][n0+nn]
        const _Float16 h = (_Float16)v;
        const size_t o = (size_t)(n0 + nn) * dim + k0 + tx;
        hiT[o] = h;
        if (loT) loT[o] = (_Float16)(v - (float)h);
    }
}

// One block per row: single pass. rowmax from pmax partials (32/row from qk8);
// P = exp(s - rowmax) fp16 (unnormalized), rowsum fp32.
__global__ __launch_bounds__(256) void softmax_p(
    const float* __restrict__ Sc, const float* __restrict__ pmax,
    _Float16* __restrict__ P, float* __restrict__ rowsum)
{
    __shared__ float red[8];
    const int tid = threadIdx.x;
    const int row = blockIdx.x;
    const float* srow = Sc + (size_t)row * 4096;
    _Float16* prow = P + (size_t)row * 4096;

    if (tid < 32) {
        float m = pmax[(size_t)row * 32 + tid];
        #pragma unroll
        for (int off = 16; off; off >>= 1) m = fmaxf(m, __shfl_xor(m, off));
        if (tid == 0) red[0] = m;
    }
    __syncthreads();
    const float rmax = red[0];

    float s = 0.f;
    for (int c = tid * 4; c < 4096; c += 1024) {
        float4 v = *(const float4*)(srow + c);
        float p0 = __expf(v.x - rmax), p1 = __expf(v.y - rmax);
        float p2 = __expf(v.z - rmax), p3 = __expf(v.w - rmax);
        s += p0 + p1 + p2 + p3;
        half4v h = {(_Float16)p0, (_Float16)p1, (_Float16)p2, (_Float16)p3};
        *(half4v*)(prow + c) = h;
    }
    #pragma unroll
    for (int off = 32; off; off >>= 1) s += __shfl_xor(s, off, 64);
    if ((tid & 63) == 0) red[4 + (tid >> 6)] = s;
    __syncthreads();
    if (tid == 0) rowsum[row] = red[4] + red[5] + red[6] + red[7];
}

extern "C" void kernel_launch(void* const* d_in, const int* in_sizes, int n_in,
                              void* d_out, int out_size, void* d_ws, size_t ws_size,
                              hipStream_t stream) {
    const int Bb = 4, S = 4096, D = 1024;
    const size_t SD = (size_t)S * D;      // 4.19M
    const size_t SS = (size_t)S * S;      // 16.8M

    const float* x  = (const float*)d_in[0];
    const float* WQ = (const float*)d_in[1];
    const float* WK = (const float*)d_in[2];
    const float* WV = (const float*)d_in[3];
    float* out = (float*)d_out;

    // Workspace layout (~204.5 MB of >=209.7 MB).
    char* w = (char*)d_ws;
    _Float16* WQhT = (_Float16*)w;  w += (size_t)D * D * 2;
    _Float16* WQlT = (_Float16*)w;  w += (size_t)D * D * 2;
    _Float16* WKhT = (_Float16*)w;  w += (size_t)D * D * 2;
    _Float16* WKlT = (_Float16*)w;  w += (size_t)D * D * 2;
    _Float16* WvhT = (_Float16*)w;  w += (size_t)D * D * 2;
    _Float16* xhi  = (_Float16*)w;  w += SD * 2;
    _Float16* xlo  = (_Float16*)w;  w += SD * 2;
    _Float16* Qhi  = (_Float16*)w;  w += SD * 2;
    _Float16* Qlo  = (_Float16*)w;  w += SD * 2;
    _Float16* Khi  = (_Float16*)w;  w += SD * 2;
    _Float16* Klo  = (_Float16*)w;  w += SD * 2;
    _Float16* VT   = (_Float16*)w;  w += SD * 2;
    float*    rowsum = (float*)w;   w += (size_t)S * 4;
    float*    pmax = (float*)w;     w += (size_t)S * 64 * 4;
    float*    Sc   = (float*)w;     w += SS * 4;
    _Float16* P    = (_Float16*)w;  w += SS * 2;
    float*    pvp  = (float*)w;     w += SD * 2 * 4;   // split-K2 f32 partials

    const float kInv256 = 0.00390625f;           // 2^-8
    const float kScScale = 4.76837158203125e-7f; // 2^-21 = 1/(65536*32)

    dim3 blk(256);

    // Weight prep: 256*W^T split fp16 (Wv: hi only), one z=3 launch.
    wprep3<<<dim3(32, 32, 3), dim3(32, 8), 0, stream>>>(
        WQ, WK, WV, WQhT, WQlT, WKhT, WKlT, WvhT, D);

    for (int b = 0; b < Bb; ++b) {
        const float* xb = x + (size_t)b * SD;
        float* outb = out + (size_t)b * SD;

        split_scale<<<dim3(4096), blk, 0, stream>>>(xb, xhi, xlo, (int)SD);

        // Q and K projections (z-fused): [4096x1024] = split(x') @ split(W'^T)
        gemm_nt<true, 3, false><<<dim3(D / 128, S / 128, 2), blk, 0, stream>>>(
            xhi, xlo, WQhT, WQlT, Qhi, Qlo, nullptr, nullptr, kInv256, S, D,
            D, D, 0, WKhT, WKlT, Khi, Klo);

        // VT'' = 256*V^T: [1024x4096] = WvhT' @ xhi'^T
        gemm_nt<false, 2, false><<<dim3(S / 128, D / 128, 1), blk, 0, stream>>>(
            WvhT, nullptr, xhi, nullptr, VT, nullptr, nullptr, nullptr, kInv256,
            D, S, D, D, 0, nullptr, nullptr, nullptr, nullptr);

        // Sc = QK^T/32 fp32 + partial rowmax: [4096x4096], 256^2 dedup chunks.
        qk8<<<dim3(S / 256, S / 256), dim3(512), 0, stream>>>(
            Qhi, Qlo, Khi, Klo, Sc, pmax, kScScale);

        softmax_p<<<dim3(S), blk, 0, stream>>>(Sc, pmax, P, rowsum);

        // PV split-K2: partial[z] = P[:, zK/2:(z+1)K/2] @ VT[:, zK/2:..]^T
        // 512 blocks = 2 blocks/CU (covers per-chunk DMA-drain stalls).
        gemm_nt<false, 0, false><<<dim3(D / 128, S / 128, 2), blk, 0, stream>>>(
            P, nullptr, VT, nullptr, pvp, nullptr, nullptr, nullptr, 1.0f,
            S, D, S / 2, S, S / 2,
            VT + S / 2, nullptr, (void*)(pvp + SD), nullptr);

        // out = (p0 + p1) * 2^-8 / rowsum
        pv_fin<<<dim3(2048), blk, 0, stream>>>(pvp, rowsum, outb, kInv256, (int)SD);
    }
}